// Round 5
// baseline (350.523 us; speedup 1.0000x reference)
//
#include <hip/hip_runtime.h>

#define INV_T 14.285714285714286f  // 1/0.07
#define C1 0.055803571428571425f   // INV_T / 256 (undoes the 16x-per-input fp8 scale)

typedef float f32x16 __attribute__((ext_vector_type(16)));
typedef long i64x2 __attribute__((ext_vector_type(2)));

__device__ __forceinline__ unsigned char f2e4m3(float f) {
    unsigned char s = (unsigned char)((__float_as_uint(f) >> 24) & 0x80);
    float a = fabsf(f);
    if (a > 448.f) a = 448.f;
    if (a == 0.f) return s;
    int e = (int)((__float_as_uint(a) >> 23) & 0xFF) - 127;
    if (e < -10) return s;
    if (e < -6) e = -6;
    float scale = __int_as_float((unsigned)(130 - e) << 23);  // 2^(3-e)
    int mi = (int)rintf(a * scale);
    if (mi >= 16) { mi >>= 1; ++e; }
    if (mi < 8) return s | (unsigned char)mi;                  // subnormal (e==-6)
    return s | (unsigned char)(((e + 7) << 3) | (mi - 8));
}

// ---- merged: fp32->fp8(x16) convert + per-row distance/Sp/counts ----
__global__ void __launch_bounds__(256) k_prep(const float* __restrict__ emb,
                                              const float* __restrict__ center,
                                              const int* __restrict__ labels,
                                              unsigned char* __restrict__ embQ,
                                              float* __restrict__ out,
                                              float* __restrict__ Sp,
                                              int* __restrict__ cnt, int D) {
    int i = blockIdx.x;
    int tid = threadIdx.x;
    const float4* row = (const float4*)(emb + (size_t)i * D);
    const float4* c4 = (const float4*)center;
    float4 e = row[tid];
    float4 c = c4[tid];
    if (embQ)
        ((uchar4*)(embQ + (size_t)i * D))[tid] =
            make_uchar4(f2e4m3(e.x * 16.f), f2e4m3(e.y * 16.f),
                        f2e4m3(e.z * 16.f), f2e4m3(e.w * 16.f));
    float dx = e.x - c.x, dy = e.y - c.y, dz = e.z - c.z, dw = e.w - c.w;
    float d2 = dx * dx + dy * dy + dz * dz + dw * dw;
    float sp = e.x * c.x + e.y * c.y + e.z * c.z + e.w * c.w;
#pragma unroll
    for (int m = 1; m <= 32; m <<= 1) {
        d2 += __shfl_xor(d2, m, 64);
        sp += __shfl_xor(sp, m, 64);
    }
    __shared__ float sd2[4], ssp[4];
    int wave = tid >> 6;
    if ((tid & 63) == 0) { sd2[wave] = d2; ssp[wave] = sp; }
    __syncthreads();
    if (tid == 0) {
        float dd = sd2[0] + sd2[1] + sd2[2] + sd2[3];
        float ss = ssp[0] + ssp[1] + ssp[2] + ssp[3];
        out[5 + i] = sqrtf(dd);
        Sp[i] = ss * INV_T;
        atomicAdd(&cnt[labels[i] == 0 ? 0 : 1], 1);
    }
}

// ---- s_m[d] = sum over machine rows of emb[:,d] ----
__global__ void __launch_bounds__(256) k_colsum(const float* __restrict__ emb,
                                                const int* __restrict__ labels,
                                                float* __restrict__ s_m, int D) {
    int t = threadIdx.x;
    int r0 = blockIdx.x * 32;
    float4 acc = {0.f, 0.f, 0.f, 0.f};
#pragma unroll 4
    for (int r = 0; r < 32; ++r) {
        float sc = (labels[r0 + r] == 0) ? 1.f : 0.f;
        float4 v = ((const float4*)(emb + (size_t)(r0 + r) * D))[t];
        acc.x += v.x * sc; acc.y += v.y * sc; acc.z += v.z * sc; acc.w += v.w * sc;
    }
    atomicAdd(&s_m[t * 4 + 0], acc.x);
    atomicAdd(&s_m[t * 4 + 1], acc.y);
    atomicAdd(&s_m[t * 4 + 2], acc.z);
    atomicAdd(&s_m[t * 4 + 3], acc.w);
}

// ---- sumexp: barrier-free register GEMM, direct-from-L2 fp8 ----
// 128x128 tiles over triangle (rb<=cb); 4 waves 2x2; wave = 64x64 via 2x2
// frags of 32x32x16_fp8_fp8. Strict grow<gcol mask => each pair counted once,
// scattered to row i and col j. NO LDS staging, NO K-loop barriers: per K-64
// group each lane loads its own contiguous 32B per fragment row (identical
// K-permutation on A and B => dot product unchanged); every 64B line fully
// consumed by one instruction pair => pure streaming from L2.
#define LOADG(off, A0, A1, B0, B1)                                   \
    do {                                                             \
        *(i64x2*)&A0[0] = *(const i64x2*)(pa0 + (off));              \
        *(i64x2*)&A0[2] = *(const i64x2*)(pa0 + (off) + 16);         \
        *(i64x2*)&A1[0] = *(const i64x2*)(pa1 + (off));              \
        *(i64x2*)&A1[2] = *(const i64x2*)(pa1 + (off) + 16);         \
        *(i64x2*)&B0[0] = *(const i64x2*)(pb0 + (off));              \
        *(i64x2*)&B0[2] = *(const i64x2*)(pb0 + (off) + 16);         \
        *(i64x2*)&B1[0] = *(const i64x2*)(pb1 + (off));              \
        *(i64x2*)&B1[2] = *(const i64x2*)(pb1 + (off) + 16);         \
    } while (0)

#define COMP(A0, A1, B0, B1)                                                        \
    do {                                                                            \
        _Pragma("unroll") for (int j = 0; j < 4; ++j) {                             \
            acc[0][0] = __builtin_amdgcn_mfma_f32_32x32x16_fp8_fp8(A0[j], B0[j], acc[0][0], 0, 0, 0); \
            acc[0][1] = __builtin_amdgcn_mfma_f32_32x32x16_fp8_fp8(A0[j], B1[j], acc[0][1], 0, 0, 0); \
            acc[1][0] = __builtin_amdgcn_mfma_f32_32x32x16_fp8_fp8(A1[j], B0[j], acc[1][0], 0, 0, 0); \
            acc[1][1] = __builtin_amdgcn_mfma_f32_32x32x16_fp8_fp8(A1[j], B1[j], acc[1][1], 0, 0, 0); \
        }                                                                           \
    } while (0)

__global__ void __launch_bounds__(256)
k_sumexp_reg(const unsigned char* __restrict__ embQ, float* __restrict__ sumexp,
             int D, int nT) {
    // decode bid -> (rb, cb), rb <= cb over nT=64 tiles of 128
    int bid = blockIdx.x;
    const int n = nT;
    float nf = (float)n + 0.5f;
    int rb = (int)(nf - sqrtf(fmaxf(nf * nf - 2.0f * (float)bid, 0.f)));
    if (rb < 0) rb = 0;
    if (rb > n - 1) rb = n - 1;
#define TRI_OFF(r) ((r) * n - ((r) * ((r)-1)) / 2)
    while (rb + 1 <= n - 1 && TRI_OFF(rb + 1) <= bid) ++rb;
    while (rb > 0 && TRI_OFF(rb) > bid) --rb;
    int cb = rb + (bid - TRI_OFF(rb));
#undef TRI_OFF
    int rowbase = rb * 128, colbase = cb * 128;

    int tid = threadIdx.x;
    int wave = tid >> 6, lane = tid & 63;
    int wr = wave >> 1, wc = wave & 1;
    int l31 = lane & 31, kk = lane >> 5;

    __shared__ float rred[2][128];
    __shared__ float cred[2][128];

    f32x16 acc[2][2];
#pragma unroll
    for (int fr = 0; fr < 2; ++fr)
#pragma unroll
        for (int fc = 0; fc < 2; ++fc)
#pragma unroll
            for (int v = 0; v < 16; ++v) acc[fr][fc][v] = 0.f;

    const unsigned char* pa0 = embQ + (size_t)(rowbase + wr * 64 + l31) * D + kk * 32;
    const unsigned char* pa1 = pa0 + (size_t)32 * D;
    const unsigned char* pb0 = embQ + (size_t)(colbase + wc * 64 + l31) * D + kk * 32;
    const unsigned char* pb1 = pb0 + (size_t)32 * D;

    long Xa0[4], Xa1[4], Xb0[4], Xb1[4];
    long Ya0[4], Ya1[4], Yb0[4], Yb1[4];

    const int kG = D >> 6;  // K-64 groups (16)
    LOADG(0, Xa0, Xa1, Xb0, Xb1);
    for (int g = 0; g < kG; g += 2) {
        if (g + 1 < kG) LOADG((g + 1) * 64, Ya0, Ya1, Yb0, Yb1);
        COMP(Xa0, Xa1, Xb0, Xb1);
        if (g + 2 < kG) LOADG((g + 2) * 64, Xa0, Xa1, Xb0, Xb1);
        if (g + 1 < kG) COMP(Ya0, Ya1, Yb0, Yb1);
    }

    // epilogue: exp over strictly-upper elements + row/col reductions
    float rs[2][16];
    float cs[2] = {0.f, 0.f};
#pragma unroll
    for (int fr = 0; fr < 2; ++fr)
#pragma unroll
        for (int v = 0; v < 16; ++v) rs[fr][v] = 0.f;

#pragma unroll
    for (int fr = 0; fr < 2; ++fr)
#pragma unroll
        for (int fc = 0; fc < 2; ++fc) {
            int gcol = colbase + wc * 64 + fc * 32 + l31;
#pragma unroll
            for (int v = 0; v < 16; ++v) {
                int grow = rowbase + wr * 64 + fr * 32 + (v & 3) + 8 * (v >> 2) + 4 * kk;
                float e = (grow < gcol) ? __expf(acc[fr][fc][v] * C1 - INV_T) : 0.f;
                rs[fr][v] += e;
                cs[fc] += e;
            }
        }

#pragma unroll
    for (int m = 1; m <= 16; m <<= 1)
#pragma unroll
        for (int fr = 0; fr < 2; ++fr)
#pragma unroll
            for (int v = 0; v < 16; ++v) rs[fr][v] += __shfl_xor(rs[fr][v], m, 64);
    if (l31 == 0)
#pragma unroll
        for (int fr = 0; fr < 2; ++fr)
#pragma unroll
            for (int v = 0; v < 16; ++v)
                rred[wc][wr * 64 + fr * 32 + (v & 3) + 8 * (v >> 2) + 4 * kk] = rs[fr][v];

#pragma unroll
    for (int fc = 0; fc < 2; ++fc) cs[fc] += __shfl_xor(cs[fc], 32, 64);
    if (kk == 0)
#pragma unroll
        for (int fc = 0; fc < 2; ++fc) cred[wr][wc * 64 + fc * 32 + l31] = cs[fc];

    __syncthreads();
    if (tid < 128) {
        atomicAdd(&sumexp[rowbase + tid], rred[0][tid] + rred[1][tid]);
    } else {
        int u = tid - 128;
        atomicAdd(&sumexp[colbase + u], cred[0][u] + cred[1][u]);
    }
}

// ---- fallback (no workspace): bf16-via-LDS path from R2 era, fp32 inline ----
typedef __bf16 bf16x8 __attribute__((ext_vector_type(8)));
typedef unsigned short u16x8 __attribute__((ext_vector_type(8)));
typedef float f32x4 __attribute__((ext_vector_type(4)));
__device__ __forceinline__ unsigned short f2bf(float f) {
    unsigned int x = __float_as_uint(f);
    x += 0x7fffu + ((x >> 16) & 1u);
    return (unsigned short)(x >> 16);
}
__global__ void __launch_bounds__(256) k_sumexp_fb(const float* __restrict__ embF,
                                                   float* __restrict__ sumexp, int D, int nTiles) {
    int bid = blockIdx.x;
    const int n = nTiles;
    float nf = (float)n + 0.5f;
    int rb = (int)(nf - sqrtf(fmaxf(nf * nf - 2.0f * (float)bid, 0.f)));
    if (rb < 0) rb = 0;
    if (rb > n - 1) rb = n - 1;
#define TRI_OFF(r) ((r) * n - ((r) * ((r)-1)) / 2)
    while (rb + 1 <= n - 1 && TRI_OFF(rb + 1) <= bid) ++rb;
    while (rb > 0 && TRI_OFF(rb) > bid) --rb;
    int cb = rb + (bid - TRI_OFF(rb));
#undef TRI_OFF
    int tid = threadIdx.x;
    int wave = tid >> 6, lane = tid & 63;
    int wr = wave >> 1, wc = wave & 1;
    int quad = lane >> 4, l15 = lane & 15;
    int rowbase = rb * 128, colbase = cb * 128;
    __shared__ unsigned short lA[128 * 64];
    __shared__ unsigned short lB[128 * 64];
    __shared__ float rred[2][128];
    __shared__ float cred[2][128];
    f32x4 zero = {0.f, 0.f, 0.f, 0.f};
    f32x4 acc[4][4];
#pragma unroll
    for (int r = 0; r < 4; ++r)
#pragma unroll
        for (int c = 0; c < 4; ++c) acc[r][c] = zero;
    const int kIters = D >> 6;
    for (int kt = 0; kt < kIters; ++kt) {
        int k0 = kt << 6;
#pragma unroll
        for (int q = 0; q < 4; ++q) {
            int ch = q * 256 + tid;
            int row = ch >> 3, lc = ch & 7;
            int pc = lc ^ (row & 7);
            const float4* sa = (const float4*)(embF + (size_t)(rowbase + row) * D + k0 + lc * 8);
            const float4* sb = (const float4*)(embF + (size_t)(colbase + row) * D + k0 + lc * 8);
            float4 a0 = sa[0], a1 = sa[1];
            float4 b0 = sb[0], b1 = sb[1];
            u16x8 va = {f2bf(a0.x), f2bf(a0.y), f2bf(a0.z), f2bf(a0.w),
                        f2bf(a1.x), f2bf(a1.y), f2bf(a1.z), f2bf(a1.w)};
            u16x8 vb = {f2bf(b0.x), f2bf(b0.y), f2bf(b0.z), f2bf(b0.w),
                        f2bf(b1.x), f2bf(b1.y), f2bf(b1.z), f2bf(b1.w)};
            *(u16x8*)&lA[(row << 6) + (pc << 3)] = va;
            *(u16x8*)&lB[(row << 6) + (pc << 3)] = vb;
        }
        __syncthreads();
#pragma unroll
        for (int h = 0; h < 2; ++h) {
            bf16x8 af[4], bfr[4];
#pragma unroll
            for (int r = 0; r < 4; ++r) {
                int row = wr * 64 + r * 16 + l15;
                int pc = (h * 4 + quad) ^ (l15 & 7);
                af[r] = *(const bf16x8*)&lA[(row << 6) + (pc << 3)];
            }
#pragma unroll
            for (int c = 0; c < 4; ++c) {
                int row = wc * 64 + c * 16 + l15;
                int pc = (h * 4 + quad) ^ (l15 & 7);
                bfr[c] = *(const bf16x8*)&lB[(row << 6) + (pc << 3)];
            }
#pragma unroll
            for (int r = 0; r < 4; ++r)
#pragma unroll
                for (int c = 0; c < 4; ++c)
                    acc[r][c] = __builtin_amdgcn_mfma_f32_16x16x32_bf16(af[r], bfr[c], acc[r][c], 0, 0, 0);
        }
        __syncthreads();
    }
    float rs[4][4], cs[4];
#pragma unroll
    for (int r = 0; r < 4; ++r)
#pragma unroll
        for (int v = 0; v < 4; ++v) rs[r][v] = 0.f;
#pragma unroll
    for (int c = 0; c < 4; ++c) cs[c] = 0.f;
#pragma unroll
    for (int r = 0; r < 4; ++r)
#pragma unroll
        for (int c = 0; c < 4; ++c) {
            f32x4 a = acc[r][c];
            int gcol = colbase + wc * 64 + c * 16 + l15;
#pragma unroll
            for (int v = 0; v < 4; ++v) {
                int grow = rowbase + wr * 64 + r * 16 + quad * 4 + v;
                float e = (grow < gcol) ? __expf((a[v] - 1.0f) * INV_T) : 0.f;
                rs[r][v] += e;
                cs[c] += e;
            }
        }
#pragma unroll
    for (int m = 1; m <= 8; m <<= 1)
#pragma unroll
        for (int r = 0; r < 4; ++r)
#pragma unroll
            for (int v = 0; v < 4; ++v) rs[r][v] += __shfl_xor(rs[r][v], m, 64);
    if (l15 == 0)
#pragma unroll
        for (int r = 0; r < 4; ++r)
#pragma unroll
            for (int v = 0; v < 4; ++v)
                rred[wc][wr * 64 + r * 16 + quad * 4 + v] = rs[r][v];
#pragma unroll
    for (int m = 16; m <= 32; m <<= 1)
#pragma unroll
        for (int c = 0; c < 4; ++c) cs[c] += __shfl_xor(cs[c], m, 64);
    if (quad == 0)
#pragma unroll
        for (int c = 0; c < 4; ++c) cred[wr][wc * 64 + c * 16 + l15] = cs[c];
    __syncthreads();
    if (tid < 128) {
        atomicAdd(&sumexp[rowbase + tid], rred[0][tid] + rred[1][tid]);
    } else {
        int u = tid & 127;
        atomicAdd(&sumexp[colbase + u], cred[0][u] + cred[1][u]);
    }
}

// ---- per-row finalize ----
__global__ void __launch_bounds__(256) k_finalize(const float* __restrict__ emb,
                                                  const float* __restrict__ s_m,
                                                  const float* __restrict__ Sp,
                                                  const float* __restrict__ sumexp,
                                                  const int* __restrict__ labels,
                                                  const float* __restrict__ outv,
                                                  const float* __restrict__ rmp,
                                                  const float* __restrict__ rhp,
                                                  float* __restrict__ scal, int D) {
    int tid = threadIdx.x;
    int wave = tid >> 6, lane = tid & 63;
    __shared__ float ac[8];
    if (tid < 8) ac[tid] = 0.f;
    __syncthreads();
    float rm = rmp[0], rh = rhp[0];
    const float4* sm4 = (const float4*)s_m;
    for (int it = 0; it < 8; ++it) {
        int i = blockIdx.x * 32 + it * 4 + wave;
        const float4* row = (const float4*)(emb + (size_t)i * D);
        float q = 0.f, sd = 0.f;
#pragma unroll
        for (int j = 0; j < 4; ++j) {
            float4 e = row[lane * 4 + j];
            float4 s = sm4[lane * 4 + j];
            q += e.x * s.x + e.y * s.y + e.z * s.z + e.w * s.w;
            sd += e.x * e.x + e.y * e.y + e.z * e.z + e.w * e.w;
        }
#pragma unroll
        for (int m = 1; m <= 32; m <<= 1) {
            q += __shfl_xor(q, m, 64);
            sd += __shfl_xor(sd, m, 64);
        }
        if (lane == 0) {
            float LP = Sp[i];
            float eS = __expf(LP - INV_T);
            float lse = INV_T + __logf(sumexp[i] + eS);
            bool mach = (labels[i] == 0);
            float pos = (q - (mach ? sd : 0.f)) * INV_T + LP;
            float d = outv[5 + i];
            atomicAdd(&ac[2], eS);
            if (mach) {
                atomicAdd(&ac[4], lse);
                atomicAdd(&ac[5], pos);
                atomicAdd(&ac[3], LP);
                float x = d - rm;
                if (x > 0.f) atomicAdd(&ac[0], x * x);
            } else {
                float x = rh - d;
                if (x > 0.f) atomicAdd(&ac[1], x * x);
            }
        }
    }
    __syncthreads();
    if (tid < 8) atomicAdd(&scal[tid], ac[tid]);
}

// ---- combine scalars ----
__global__ void k_final(const float* __restrict__ scal, const int* __restrict__ cnt,
                        float* __restrict__ out) {
    if (threadIdx.x == 0) {
        int nm = cnt[0], nh = cnt[1];
        float nmf = (float)(nm > 1 ? nm : 1);
        float nhf = (float)(nh > 1 ? nh : 1);
        float loss_m = scal[0] / nmf;
        float loss_h = scal[1] / nhf;
        float loss_shell = loss_m + loss_h;
        float lse_p = INV_T + __logf(scal[2]);
        float proto = lse_p - scal[3] / nmf;
        float con = scal[4] - scal[5] / nmf;
        int denom = (nm + 1 > 1) ? nm + 1 : 1;
        float lc = (con + proto) / (float)denom;
        if (!(nm > 0 && nh > 0)) lc = 0.f;
        out[0] = loss_shell + lc;
        out[1] = loss_shell;
        out[2] = loss_m;
        out[3] = loss_h;
        out[4] = lc;
    }
}

extern "C" void kernel_launch(void* const* d_in, const int* in_sizes, int n_in,
                              void* d_out, int out_size, void* d_ws, size_t ws_size,
                              hipStream_t stream) {
    const float* emb = (const float*)d_in[0];
    const float* center = (const float*)d_in[1];
    const float* rmp = (const float*)d_in[2];
    const float* rhp = (const float*)d_in[3];
    const int* labels = (const int*)d_in[4];
    float* out = (float*)d_out;
    const int B = in_sizes[4];
    const int D = in_sizes[1];

    size_t qBytes = (size_t)B * D;  // fp8 copy
    size_t auxBytes = (size_t)B * 4 + (size_t)D * 4 + 256 + (size_t)B * 4;
    bool pre = ws_size >= qBytes + auxBytes;
    size_t Z0 = pre ? qBytes : 0;

    char* ws = (char*)d_ws;
    unsigned char* embQ = (unsigned char*)ws;
    float* sumexp = (float*)(ws + Z0);
    float* s_m = (float*)(ws + Z0 + (size_t)B * 4);
    float* scal = (float*)(ws + Z0 + (size_t)B * 4 + (size_t)D * 4);
    int* cnt = (int*)(scal + 8);
    float* Sp = (float*)(ws + Z0 + (size_t)B * 4 + (size_t)D * 4 + 256);

    hipMemsetAsync(ws + Z0, 0, (size_t)B * 4 + (size_t)D * 4 + 256, stream);

    k_prep<<<B, D / 4, 0, stream>>>(emb, center, labels, pre ? embQ : nullptr, out, Sp, cnt, D);
    k_colsum<<<B / 32, D / 4, 0, stream>>>(emb, labels, s_m, D);

    int nT = B / 128;
    int nBlocks = nT * (nT + 1) / 2;
    if (pre) k_sumexp_reg<<<nBlocks, 256, 0, stream>>>(embQ, sumexp, D, nT);
    else     k_sumexp_fb<<<nBlocks, 256, 0, stream>>>(emb, sumexp, D, nT);

    k_finalize<<<B / 32, 256, 0, stream>>>(emb, s_m, Sp, sumexp, labels, out, rmp, rhp, scal, D);
    k_final<<<1, 64, 0, stream>>>(scal, cnt, out);
}

// Round 6
// 309.507 us; speedup vs baseline: 1.1325x; 1.1325x over previous
//
#include <hip/hip_runtime.h>

#define INV_T 14.285714285714286f  // 1/0.07
#define C1 0.055803571428571425f   // INV_T / 256 (undoes the 16x-per-input fp8 scale)

typedef float f32x16 __attribute__((ext_vector_type(16)));
typedef float f32x4 __attribute__((ext_vector_type(4)));
typedef int i32x4v __attribute__((ext_vector_type(4)));
typedef int i32x8 __attribute__((ext_vector_type(8)));

__device__ __forceinline__ unsigned char f2e4m3(float f) {
    unsigned char s = (unsigned char)((__float_as_uint(f) >> 24) & 0x80);
    float a = fabsf(f);
    if (a > 448.f) a = 448.f;
    if (a == 0.f) return s;
    int e = (int)((__float_as_uint(a) >> 23) & 0xFF) - 127;
    if (e < -10) return s;
    if (e < -6) e = -6;
    float scale = __int_as_float((unsigned)(130 - e) << 23);  // 2^(3-e)
    int mi = (int)rintf(a * scale);
    if (mi >= 16) { mi >>= 1; ++e; }
    if (mi < 8) return s | (unsigned char)mi;                  // subnormal (e==-6)
    return s | (unsigned char)(((e + 7) << 3) | (mi - 8));
}

__device__ __forceinline__ void async16(void* l, const void* g) {
    __builtin_amdgcn_global_load_lds(
        (const __attribute__((address_space(1))) unsigned int*)g,
        (__attribute__((address_space(3))) unsigned int*)l, 16, 0, 0);
}

// ---- merged: fp32->fp8(x16) convert + per-row distance/Sp/counts ----
__global__ void __launch_bounds__(256) k_prep(const float* __restrict__ emb,
                                              const float* __restrict__ center,
                                              const int* __restrict__ labels,
                                              unsigned char* __restrict__ embQ,
                                              float* __restrict__ out,
                                              float* __restrict__ Sp,
                                              int* __restrict__ cnt, int D) {
    int i = blockIdx.x;
    int tid = threadIdx.x;
    const float4* row = (const float4*)(emb + (size_t)i * D);
    const float4* c4 = (const float4*)center;
    float4 e = row[tid];
    float4 c = c4[tid];
    if (embQ)
        ((uchar4*)(embQ + (size_t)i * D))[tid] =
            make_uchar4(f2e4m3(e.x * 16.f), f2e4m3(e.y * 16.f),
                        f2e4m3(e.z * 16.f), f2e4m3(e.w * 16.f));
    float dx = e.x - c.x, dy = e.y - c.y, dz = e.z - c.z, dw = e.w - c.w;
    float d2 = dx * dx + dy * dy + dz * dz + dw * dw;
    float sp = e.x * c.x + e.y * c.y + e.z * c.z + e.w * c.w;
#pragma unroll
    for (int m = 1; m <= 32; m <<= 1) {
        d2 += __shfl_xor(d2, m, 64);
        sp += __shfl_xor(sp, m, 64);
    }
    __shared__ float sd2[4], ssp[4];
    int wave = tid >> 6;
    if ((tid & 63) == 0) { sd2[wave] = d2; ssp[wave] = sp; }
    __syncthreads();
    if (tid == 0) {
        float dd = sd2[0] + sd2[1] + sd2[2] + sd2[3];
        float ss = ssp[0] + ssp[1] + ssp[2] + ssp[3];
        out[5 + i] = sqrtf(dd);
        Sp[i] = ss * INV_T;
        atomicAdd(&cnt[labels[i] == 0 ? 0 : 1], 1);
    }
}

// ---- s_m[d] = sum over machine rows of emb[:,d] ----
__global__ void __launch_bounds__(256) k_colsum(const float* __restrict__ emb,
                                                const int* __restrict__ labels,
                                                float* __restrict__ s_m, int D) {
    int t = threadIdx.x;
    int r0 = blockIdx.x * 32;
    float4 acc = {0.f, 0.f, 0.f, 0.f};
#pragma unroll 4
    for (int r = 0; r < 32; ++r) {
        float sc = (labels[r0 + r] == 0) ? 1.f : 0.f;
        float4 v = ((const float4*)(emb + (size_t)(r0 + r) * D))[t];
        acc.x += v.x * sc; acc.y += v.y * sc; acc.z += v.z * sc; acc.w += v.w * sc;
    }
    atomicAdd(&s_m[t * 4 + 0], acc.x);
    atomicAdd(&s_m[t * 4 + 1], acc.y);
    atomicAdd(&s_m[t * 4 + 2], acc.z);
    atomicAdd(&s_m[t * 4 + 3], acc.w);
}

// ---- sumexp via MX-scaled fp8 MFMA (K=64/instr, scales = 1.0) ----
// 128x128 tiles over triangle (rb<=cb); 4 waves, wave = 64x64 via 2x2 frags
// of mfma_scale_f32_32x32x64_f8f6f4. K-tile = 128, double-buffered LDS
// (2 x 32 KB -> 2 blocks/CU). LDS layout c-major in 16B chunks:
// slot = chunkcol*128 + row -> lane-contiguous conflict-free ds_read_b128,
// and DMA dest (wave-uniform base + lane*16) maps to consecutive rows.
__global__ void __launch_bounds__(256, 2)
k_sumexp_mx(const unsigned char* __restrict__ embQ, float* __restrict__ sumexp,
            int D, int nT) {
    int bid = blockIdx.x;
    const int n = nT;
    float nf = (float)n + 0.5f;
    int rb = (int)(nf - sqrtf(fmaxf(nf * nf - 2.0f * (float)bid, 0.f)));
    if (rb < 0) rb = 0;
    if (rb > n - 1) rb = n - 1;
#define TRI_OFF(r) ((r) * n - ((r) * ((r)-1)) / 2)
    while (rb + 1 <= n - 1 && TRI_OFF(rb + 1) <= bid) ++rb;
    while (rb > 0 && TRI_OFF(rb) > bid) --rb;
    int cb = rb + (bid - TRI_OFF(rb));
#undef TRI_OFF
    int rowbase = rb * 128, colbase = cb * 128;

    int tid = threadIdx.x;
    int wave = tid >> 6, lane = tid & 63;
    int wr = wave >> 1, wc = wave & 1;
    int l31 = lane & 31, kk = lane >> 5;

    __shared__ unsigned char sA[2][16384];  // 128 rows x 8 chunks (K=128)
    __shared__ unsigned char sB[2][16384];
    __shared__ float rred[2][128];
    __shared__ float cred[2][128];

    f32x16 acc[2][2];
#pragma unroll
    for (int fr = 0; fr < 2; ++fr)
#pragma unroll
        for (int fc = 0; fc < 2; ++fc)
#pragma unroll
            for (int v = 0; v < 16; ++v) acc[fr][fc][v] = 0.f;

    const int kG = D >> 7;  // K-tiles of 128 (8)

    // staging: 1024 chunks each for A and B; thread handles 4+4
    int r0 = tid & 127, c0 = tid >> 7;  // chunk ch = q*256+tid -> row = ch&127, col = c0 + q*2
    const unsigned char* gA = embQ + (size_t)(rowbase + r0) * D + c0 * 16;
    const unsigned char* gB = embQ + (size_t)(colbase + r0) * D + c0 * 16;

    auto stage = [&](int buf, int kt) {
        int ko = kt << 7;
#pragma unroll
        for (int q = 0; q < 4; ++q) {
            int ch = q * 256 + tid;
            async16(&sA[buf][ch << 4], gA + ko + q * 32);
            async16(&sB[buf][ch << 4], gB + ko + q * 32);
        }
    };

    stage(0, 0);
    for (int kt = 0; kt < kG; ++kt) {
        int cur = kt & 1;
        __syncthreads();                       // cur DMA complete, prev reads done
        if (kt + 1 < kG) stage(cur ^ 1, kt + 1);  // prefetch in flight during compute
        const unsigned char* A = sA[cur];
        const unsigned char* Bp = sB[cur];
#pragma unroll
        for (int h = 0; h < 2; ++h) {          // two K-64 halves
            int cc = 4 * h + 2 * kk;           // starting 16B chunk-col for this lane
            i32x8 av[2], bv[2];
#pragma unroll
            for (int fr = 0; fr < 2; ++fr) {
                int r = wr * 64 + fr * 32 + l31;
                i32x4v lo = *(const i32x4v*)&A[(cc * 128 + r) << 4];
                i32x4v hi = *(const i32x4v*)&A[((cc + 1) * 128 + r) << 4];
                av[fr] = __builtin_shufflevector(lo, hi, 0, 1, 2, 3, 4, 5, 6, 7);
            }
#pragma unroll
            for (int fc = 0; fc < 2; ++fc) {
                int r = wc * 64 + fc * 32 + l31;
                i32x4v lo = *(const i32x4v*)&Bp[(cc * 128 + r) << 4];
                i32x4v hi = *(const i32x4v*)&Bp[((cc + 1) * 128 + r) << 4];
                bv[fc] = __builtin_shufflevector(lo, hi, 0, 1, 2, 3, 4, 5, 6, 7);
            }
#pragma unroll
            for (int fr = 0; fr < 2; ++fr)
#pragma unroll
                for (int fc = 0; fc < 2; ++fc)
                    acc[fr][fc] = __builtin_amdgcn_mfma_scale_f32_32x32x64_f8f6f4(
                        av[fr], bv[fc], acc[fr][fc], 0, 0,
                        0, 0x7F7F7F7F, 0, 0x7F7F7F7F);  // fp8/fp8, scales = 1.0
        }
    }

    // epilogue: exp over strictly-upper elements + row/col reductions
    float rs[2][16];
    float cs[2] = {0.f, 0.f};
#pragma unroll
    for (int fr = 0; fr < 2; ++fr)
#pragma unroll
        for (int v = 0; v < 16; ++v) rs[fr][v] = 0.f;

#pragma unroll
    for (int fr = 0; fr < 2; ++fr)
#pragma unroll
        for (int fc = 0; fc < 2; ++fc) {
            int gcol = colbase + wc * 64 + fc * 32 + l31;
#pragma unroll
            for (int v = 0; v < 16; ++v) {
                int grow = rowbase + wr * 64 + fr * 32 + (v & 3) + 8 * (v >> 2) + 4 * kk;
                float e = (grow < gcol) ? __expf(acc[fr][fc][v] * C1 - INV_T) : 0.f;
                rs[fr][v] += e;
                cs[fc] += e;
            }
        }

#pragma unroll
    for (int m = 1; m <= 16; m <<= 1)
#pragma unroll
        for (int fr = 0; fr < 2; ++fr)
#pragma unroll
            for (int v = 0; v < 16; ++v) rs[fr][v] += __shfl_xor(rs[fr][v], m, 64);
    if (l31 == 0)
#pragma unroll
        for (int fr = 0; fr < 2; ++fr)
#pragma unroll
            for (int v = 0; v < 16; ++v)
                rred[wc][wr * 64 + fr * 32 + (v & 3) + 8 * (v >> 2) + 4 * kk] = rs[fr][v];

#pragma unroll
    for (int fc = 0; fc < 2; ++fc) cs[fc] += __shfl_xor(cs[fc], 32, 64);
    if (kk == 0)
#pragma unroll
        for (int fc = 0; fc < 2; ++fc) cred[wr][wc * 64 + fc * 32 + l31] = cs[fc];

    __syncthreads();
    if (tid < 128) {
        atomicAdd(&sumexp[rowbase + tid], rred[0][tid] + rred[1][tid]);
    } else {
        int u = tid - 128;
        atomicAdd(&sumexp[colbase + u], cred[0][u] + cred[1][u]);
    }
}

// ---- fallback (no workspace): bf16-via-LDS, fp32 inline convert ----
typedef __bf16 bf16x8 __attribute__((ext_vector_type(8)));
typedef unsigned short u16x8 __attribute__((ext_vector_type(8)));
__device__ __forceinline__ unsigned short f2bf(float f) {
    unsigned int x = __float_as_uint(f);
    x += 0x7fffu + ((x >> 16) & 1u);
    return (unsigned short)(x >> 16);
}
__global__ void __launch_bounds__(256) k_sumexp_fb(const float* __restrict__ embF,
                                                   float* __restrict__ sumexp, int D, int nTiles) {
    int bid = blockIdx.x;
    const int n = nTiles;
    float nf = (float)n + 0.5f;
    int rb = (int)(nf - sqrtf(fmaxf(nf * nf - 2.0f * (float)bid, 0.f)));
    if (rb < 0) rb = 0;
    if (rb > n - 1) rb = n - 1;
#define TRI_OFF(r) ((r) * n - ((r) * ((r)-1)) / 2)
    while (rb + 1 <= n - 1 && TRI_OFF(rb + 1) <= bid) ++rb;
    while (rb > 0 && TRI_OFF(rb) > bid) --rb;
    int cb = rb + (bid - TRI_OFF(rb));
#undef TRI_OFF
    int tid = threadIdx.x;
    int wave = tid >> 6, lane = tid & 63;
    int wr = wave >> 1, wc = wave & 1;
    int quad = lane >> 4, l15 = lane & 15;
    int rowbase = rb * 128, colbase = cb * 128;
    __shared__ unsigned short lA[128 * 64];
    __shared__ unsigned short lB[128 * 64];
    __shared__ float rred[2][128];
    __shared__ float cred[2][128];
    f32x4 zero = {0.f, 0.f, 0.f, 0.f};
    f32x4 acc[4][4];
#pragma unroll
    for (int r = 0; r < 4; ++r)
#pragma unroll
        for (int c = 0; c < 4; ++c) acc[r][c] = zero;
    const int kIters = D >> 6;
    for (int kt = 0; kt < kIters; ++kt) {
        int k0 = kt << 6;
#pragma unroll
        for (int q = 0; q < 4; ++q) {
            int ch = q * 256 + tid;
            int row = ch >> 3, lc = ch & 7;
            int pc = lc ^ (row & 7);
            const float4* sa = (const float4*)(embF + (size_t)(rowbase + row) * D + k0 + lc * 8);
            const float4* sb = (const float4*)(embF + (size_t)(colbase + row) * D + k0 + lc * 8);
            float4 a0 = sa[0], a1 = sa[1];
            float4 b0 = sb[0], b1 = sb[1];
            u16x8 va = {f2bf(a0.x), f2bf(a0.y), f2bf(a0.z), f2bf(a0.w),
                        f2bf(a1.x), f2bf(a1.y), f2bf(a1.z), f2bf(a1.w)};
            u16x8 vb = {f2bf(b0.x), f2bf(b0.y), f2bf(b0.z), f2bf(b0.w),
                        f2bf(b1.x), f2bf(b1.y), f2bf(b1.z), f2bf(b1.w)};
            *(u16x8*)&lA[(row << 6) + (pc << 3)] = va;
            *(u16x8*)&lB[(row << 6) + (pc << 3)] = vb;
        }
        __syncthreads();
#pragma unroll
        for (int h = 0; h < 2; ++h) {
            bf16x8 af[4], bfr[4];
#pragma unroll
            for (int r = 0; r < 4; ++r) {
                int row = wr * 64 + r * 16 + l15;
                int pc = (h * 4 + quad) ^ (l15 & 7);
                af[r] = *(const bf16x8*)&lA[(row << 6) + (pc << 3)];
            }
#pragma unroll
            for (int c = 0; c < 4; ++c) {
                int row = wc * 64 + c * 16 + l15;
                int pc = (h * 4 + quad) ^ (l15 & 7);
                bfr[c] = *(const bf16x8*)&lB[(row << 6) + (pc << 3)];
            }
#pragma unroll
            for (int r = 0; r < 4; ++r)
#pragma unroll
                for (int c = 0; c < 4; ++c)
                    acc[r][c] = __builtin_amdgcn_mfma_f32_16x16x32_bf16(af[r], bfr[c], acc[r][c], 0, 0, 0);
        }
        __syncthreads();
    }
    float rs[4][4], cs[4];
#pragma unroll
    for (int r = 0; r < 4; ++r)
#pragma unroll
        for (int v = 0; v < 4; ++v) rs[r][v] = 0.f;
#pragma unroll
    for (int c = 0; c < 4; ++c) cs[c] = 0.f;
#pragma unroll
    for (int r = 0; r < 4; ++r)
#pragma unroll
        for (int c = 0; c < 4; ++c) {
            f32x4 a = acc[r][c];
            int gcol = colbase + wc * 64 + c * 16 + l15;
#pragma unroll
            for (int v = 0; v < 4; ++v) {
                int grow = rowbase + wr * 64 + r * 16 + quad * 4 + v;
                float e = (grow < gcol) ? __expf((a[v] - 1.0f) * INV_T) : 0.f;
                rs[r][v] += e;
                cs[c] += e;
            }
        }
#pragma unroll
    for (int m = 1; m <= 8; m <<= 1)
#pragma unroll
        for (int r = 0; r < 4; ++r)
#pragma unroll
            for (int v = 0; v < 4; ++v) rs[r][v] += __shfl_xor(rs[r][v], m, 64);
    if (l15 == 0)
#pragma unroll
        for (int r = 0; r < 4; ++r)
#pragma unroll
            for (int v = 0; v < 4; ++v)
                rred[wc][wr * 64 + r * 16 + quad * 4 + v] = rs[r][v];
#pragma unroll
    for (int m = 16; m <= 32; m <<= 1)
#pragma unroll
        for (int c = 0; c < 4; ++c) cs[c] += __shfl_xor(cs[c], m, 64);
    if (quad == 0)
#pragma unroll
        for (int c = 0; c < 4; ++c) cred[wr][wc * 64 + c * 16 + l15] = cs[c];
    __syncthreads();
    if (tid < 128) {
        atomicAdd(&sumexp[rowbase + tid], rred[0][tid] + rred[1][tid]);
    } else {
        int u = tid & 127;
        atomicAdd(&sumexp[colbase + u], cred[0][u] + cred[1][u]);
    }
}

// ---- per-row finalize ----
__global__ void __launch_bounds__(256) k_finalize(const float* __restrict__ emb,
                                                  const float* __restrict__ s_m,
                                                  const float* __restrict__ Sp,
                                                  const float* __restrict__ sumexp,
                                                  const int* __restrict__ labels,
                                                  const float* __restrict__ outv,
                                                  const float* __restrict__ rmp,
                                                  const float* __restrict__ rhp,
                                                  float* __restrict__ scal, int D) {
    int tid = threadIdx.x;
    int wave = tid >> 6, lane = tid & 63;
    __shared__ float ac[8];
    if (tid < 8) ac[tid] = 0.f;
    __syncthreads();
    float rm = rmp[0], rh = rhp[0];
    const float4* sm4 = (const float4*)s_m;
    for (int it = 0; it < 8; ++it) {
        int i = blockIdx.x * 32 + it * 4 + wave;
        const float4* row = (const float4*)(emb + (size_t)i * D);
        float q = 0.f, sd = 0.f;
#pragma unroll
        for (int j = 0; j < 4; ++j) {
            float4 e = row[lane * 4 + j];
            float4 s = sm4[lane * 4 + j];
            q += e.x * s.x + e.y * s.y + e.z * s.z + e.w * s.w;
            sd += e.x * e.x + e.y * e.y + e.z * e.z + e.w * e.w;
        }
#pragma unroll
        for (int m = 1; m <= 32; m <<= 1) {
            q += __shfl_xor(q, m, 64);
            sd += __shfl_xor(sd, m, 64);
        }
        if (lane == 0) {
            float LP = Sp[i];
            float eS = __expf(LP - INV_T);
            float lse = INV_T + __logf(sumexp[i] + eS);
            bool mach = (labels[i] == 0);
            float pos = (q - (mach ? sd : 0.f)) * INV_T + LP;
            float d = outv[5 + i];
            atomicAdd(&ac[2], eS);
            if (mach) {
                atomicAdd(&ac[4], lse);
                atomicAdd(&ac[5], pos);
                atomicAdd(&ac[3], LP);
                float x = d - rm;
                if (x > 0.f) atomicAdd(&ac[0], x * x);
            } else {
                float x = rh - d;
                if (x > 0.f) atomicAdd(&ac[1], x * x);
            }
        }
    }
    __syncthreads();
    if (tid < 8) atomicAdd(&scal[tid], ac[tid]);
}

// ---- combine scalars ----
__global__ void k_final(const float* __restrict__ scal, const int* __restrict__ cnt,
                        float* __restrict__ out) {
    if (threadIdx.x == 0) {
        int nm = cnt[0], nh = cnt[1];
        float nmf = (float)(nm > 1 ? nm : 1);
        float nhf = (float)(nh > 1 ? nh : 1);
        float loss_m = scal[0] / nmf;
        float loss_h = scal[1] / nhf;
        float loss_shell = loss_m + loss_h;
        float lse_p = INV_T + __logf(scal[2]);
        float proto = lse_p - scal[3] / nmf;
        float con = scal[4] - scal[5] / nmf;
        int denom = (nm + 1 > 1) ? nm + 1 : 1;
        float lc = (con + proto) / (float)denom;
        if (!(nm > 0 && nh > 0)) lc = 0.f;
        out[0] = loss_shell + lc;
        out[1] = loss_shell;
        out[2] = loss_m;
        out[3] = loss_h;
        out[4] = lc;
    }
}

extern "C" void kernel_launch(void* const* d_in, const int* in_sizes, int n_in,
                              void* d_out, int out_size, void* d_ws, size_t ws_size,
                              hipStream_t stream) {
    const float* emb = (const float*)d_in[0];
    const float* center = (const float*)d_in[1];
    const float* rmp = (const float*)d_in[2];
    const float* rhp = (const float*)d_in[3];
    const int* labels = (const int*)d_in[4];
    float* out = (float*)d_out;
    const int B = in_sizes[4];
    const int D = in_sizes[1];

    size_t qBytes = (size_t)B * D;  // fp8 copy
    size_t auxBytes = (size_t)B * 4 + (size_t)D * 4 + 256 + (size_t)B * 4;
    bool pre = ws_size >= qBytes + auxBytes;
    size_t Z0 = pre ? qBytes : 0;

    char* ws = (char*)d_ws;
    unsigned char* embQ = (unsigned char*)ws;
    float* sumexp = (float*)(ws + Z0);
    float* s_m = (float*)(ws + Z0 + (size_t)B * 4);
    float* scal = (float*)(ws + Z0 + (size_t)B * 4 + (size_t)D * 4);
    int* cnt = (int*)(scal + 8);
    float* Sp = (float*)(ws + Z0 + (size_t)B * 4 + (size_t)D * 4 + 256);

    hipMemsetAsync(ws + Z0, 0, (size_t)B * 4 + (size_t)D * 4 + 256, stream);

    k_prep<<<B, D / 4, 0, stream>>>(emb, center, labels, pre ? embQ : nullptr, out, Sp, cnt, D);
    k_colsum<<<B / 32, D / 4, 0, stream>>>(emb, labels, s_m, D);

    int nT = B / 128;
    int nBlocks = nT * (nT + 1) / 2;
    if (pre) k_sumexp_mx<<<nBlocks, 256, 0, stream>>>(embQ, sumexp, D, nT);
    else     k_sumexp_fb<<<nBlocks, 256, 0, stream>>>(emb, sumexp, D, nT);

    k_finalize<<<B / 32, 256, 0, stream>>>(emb, s_m, Sp, sumexp, labels, out, rmp, rhp, scal, D);
    k_final<<<1, 64, 0, stream>>>(scal, cnt, out);
}